// Round 11
// baseline (537.216 us; speedup 1.0000x reference)
//
#include <hip/hip_runtime.h>
#include <stdint.h>

typedef unsigned short u16;
typedef __bf16 bf16x8 __attribute__((ext_vector_type(8)));
typedef float f32x4 __attribute__((ext_vector_type(4)));

#define B_ 8
#define N_ 7057
#define MTOT 56456
#define SCALING_F (1.0f/64.0f)

// ws layout (bytes, 16-aligned).
#define Z_OFF    0ull               // f32 z: 14,452,736
#define LORA_OFF 14452736ull        // bf16 lora: 7,226,368
#define GIDX_OFF 21679104ull        // int gate_idx[8] (+pad)
#define CWT_OFF  21679360ull        // bf16 conv_wt: 221,184 (co-row XOR-swizzled)
#define W0B_OFF  21900544ull        // bf16 W0: 2,097,152
#define WDB_OFF  23997696ull        // bf16 W_down: 131,072
#define WUB_OFF  24128768ull        // bf16 W_up: 131,072
#define UP_OFF   24259840ull        // pp[8][56][64] f32 gate scratch
#define CO_OFF   139865344ull       // bf16 convout: 115,605,504 (ends 255,470,848)
#define XB_OFF   255470848ull       // bf16 xb [MTOT][1024]: 115,621,888 (fast path only)
#define WS_FAST  371092736ull       // bytes needed for fast path
#define UPB_STRIDE ((size_t)112896 * 64)  // per-batch elems (max rate 4)

__device__ __forceinline__ u16 f2b(float f) {
  __bf16 h = (__bf16)f;           // RNE
  union { __bf16 h; u16 u; } v; v.h = h; return v.u;
}
__device__ __forceinline__ float b2f(u16 u) {
  union { uint32_t i; float f; } v; v.i = ((uint32_t)u) << 16; return v.f;
}
__device__ __forceinline__ void gload_lds16(const void* g, void* l) {
  __builtin_amdgcn_global_load_lds(
      (const __attribute__((address_space(1))) uint32_t*)g,
      (__attribute__((address_space(3))) uint32_t*)l, 16, 0, 0);
}
__device__ __forceinline__ f32x4 mfma16(bf16x8 a, bf16x8 b, f32x4 c) {
  return __builtin_amdgcn_mfma_f32_16x16x32_bf16(a, b, c, 0, 0, 0);
}
__device__ __forceinline__ bf16x8 cvt8(float4 a, float4 b) {
  bf16x8 v;
  v[0] = (__bf16)a.x; v[1] = (__bf16)a.y; v[2] = (__bf16)a.z; v[3] = (__bf16)a.w;
  v[4] = (__bf16)b.x; v[5] = (__bf16)b.y; v[6] = (__bf16)b.z; v[7] = (__bf16)b.w;
  return v;
}
__device__ __forceinline__ float cubicw(float t) {
  const float a = -0.75f;
  float at = fabsf(t);
  float w1 = ((a + 2.0f) * at - (a + 3.0f)) * at * at + 1.0f;
  float w2 = (((at - 5.0f) * at + 8.0f) * at - 4.0f) * a;
  return at <= 1.0f ? w1 : (at < 2.0f ? w2 : 0.0f);
}
__device__ __forceinline__ int iclamp(int v, int lo, int hi) { return v < lo ? lo : (v > hi ? hi : v); }
__device__ __forceinline__ int rate_of(int e) { return e == 0 ? 2 : (e == 1 ? 1 : 4); }

// ---------------- Kernel 0: merged f32 -> bf16 weight convert (W0|Wd|Wup contiguous) ----------------
__global__ __launch_bounds__(256) void cvtall_kernel(const float* __restrict__ W0, const float* __restrict__ Wd,
                                                     const float* __restrict__ Wup, u16* __restrict__ dst) {
  int i = (blockIdx.x * 256 + threadIdx.x) * 4;      // total 1,179,648 elems
  if (i >= 1179648) return;
  const float* src;
  if (i < 1048576)      src = W0 + i;
  else if (i < 1114112) src = Wd + (i - 1048576);
  else                  src = Wup + (i - 1114112);
  float4 v = *(const float4*)src;
  union { u16 u[4]; uint2 q; } p;
  p.u[0] = f2b(v.x); p.u[1] = f2b(v.y); p.u[2] = f2b(v.z); p.u[3] = f2b(v.w);
  *(uint2*)(dst + i) = p.q;
}

// ---------------- Kernel 0b (fallback): x f32 -> bf16 grid-stride ----------------
__global__ __launch_bounds__(256) void cvtx_kernel(const float* __restrict__ x, u16* __restrict__ xb) {
  size_t stride = (size_t)gridDim.x * 256 * 8;
  for (size_t i = ((size_t)blockIdx.x * 256 + threadIdx.x) * 8; i < (size_t)MTOT * 1024; i += stride) {
    float4 a = *(const float4*)(x + i);
    float4 b = *(const float4*)(x + i + 4);
    *(bf16x8*)(xb + i) = cvt8(a, b);
  }
}

// ---------------- Kernel 1: z = x @ W_down^T -> f32; side-writes xb (bf16 x) ----------------
// BARRIER-FREE: each lane loads+converts its own MFMA A-fragment directly from global
// (lane l: row l&15, k-oct l>>4 — lanes pair into full 64B lines). B-frags read per-lane
// from L2-resident Wdb (128 KB). No LDS, no __syncthreads, high occupancy.
__global__ __launch_bounds__(256) void zgemm_kernel(const float* __restrict__ x,
                                                    const u16* __restrict__ Wdb,
                                                    float* __restrict__ z,
                                                    u16* __restrict__ xb) {
  const int tid = threadIdx.x;
  const int lane = tid & 63;
  const int w = tid >> 6;
  const int row0 = blockIdx.x * 64 + w * 16;   // wave owns 16 rows
  const int rl = lane & 15;
  const int ko = lane >> 4;                    // k-oct group 0..3
  int arow = row0 + rl; if (arow >= MTOT) arow = MTOT - 1;
  const float* ax = x + (size_t)arow * 1024 + ko * 8;
  u16* axb = xb ? (xb + (size_t)arow * 1024 + ko * 8) : nullptr;
  const u16* bw = Wdb + (size_t)rl * 1024 + ko * 8;   // + fc*16*1024 per frag
  f32x4 acc[4] = {{0,0,0,0},{0,0,0,0},{0,0,0,0},{0,0,0,0}};
  for (int k0 = 0; k0 < 1024; k0 += 32) {
    float4 q0 = *(const float4*)(ax + k0);
    float4 q1 = *(const float4*)(ax + k0 + 4);
    bf16x8 a = cvt8(q0, q1);
    if (axb) *(bf16x8*)(axb + k0) = a;   // bf16 x side-product (fast path)
#pragma unroll
    for (int fc = 0; fc < 4; ++fc) {
      bf16x8 b = *(const bf16x8*)(bw + (size_t)fc * 16 * 1024 + k0);
      acc[fc] = mfma16(a, b, acc[fc]);
    }
  }
  const int crow = (lane >> 4) * 4, ccol = lane & 15;
#pragma unroll
  for (int fc = 0; fc < 4; ++fc) {
#pragma unroll
    for (int i = 0; i < 4; ++i) {
      int gr = row0 + crow + i;
      if (gr < MTOT) z[(size_t)gr * 64 + fc * 16 + ccol] = acc[fc][i];
    }
  }
}

// ---------------- Kernel 2a: conv weight transpose -> bf16[e][tap][co][ci-swizzled] ----------------
__global__ __launch_bounds__(256) void convwt_kernel(const float* __restrict__ cw, u16* __restrict__ cwt) {
  int idx = blockIdx.x * 256 + threadIdx.x;          // 3*9*64*64 = 110592 total
  if (idx >= 3 * 9 * 64 * 64) return;
  int ci = idx & 63;
  int co = (idx >> 6) & 63;
  int rest = idx >> 12;           // e*9 + tap
  int tap = rest % 9;
  int e = rest / 9;
  int sw = ((((ci >> 3) ^ (co & 7)) << 3) | (ci & 7));
  cwt[(((size_t)rest * 64) + co) * 64 + sw] = f2b(cw[((size_t)(e * 64 + co) * 64 + ci) * 9 + tap]);
}

// ---------------- Kernel 2b: gate stage 1 — per-chunk partial channel sums ----------------
__global__ __launch_bounds__(256) void gate1_kernel(const float* __restrict__ z, float* __restrict__ pp) {
  int b = blockIdx.y, q = blockIdx.x;   // q in [0,56)
  int tid = threadIdx.x;
  int c = tid & 63, part = tid >> 6;
  const float* zb = z + (size_t)b * N_ * 64;
  int n0 = 1 + q * 126;
  float s = 0.0f;
  for (int n = n0 + part; n < n0 + 126; n += 4) s += zb[(size_t)n * 64 + c];
  __shared__ float red[4][64];
  red[part][c] = s;
  __syncthreads();
  if (tid < 64)
    pp[((size_t)b * 56 + q) * 64 + tid] = red[0][tid] + red[1][tid] + red[2][tid] + red[3][tid];
}

// ---------------- Kernel 2c: gate stage 2 — pooled mean, scores, argmax, cls row ----------------
__global__ __launch_bounds__(64) void gate2_kernel(const float* __restrict__ pp, const float* __restrict__ z,
                                                   const float* __restrict__ Wg, const float* __restrict__ bg,
                                                   int* __restrict__ gidx, u16* __restrict__ lora) {
  int b = blockIdx.x;
  int c = threadIdx.x;                  // 0..63
  float s = 0.0f;
  for (int q = 0; q < 56; ++q) s += pp[((size_t)b * 56 + q) * 64 + c];
  __shared__ float pl[64];
  pl[c] = s * (1.0f / 7056.0f);
  const float* zb = z + (size_t)b * N_ * 64;
  lora[(size_t)b * N_ * 64 + c] = f2b(zb[c]);   // cls_embed, NOT scaled
  __syncthreads();
  if (c == 0) {
    float best = 0.0f; int bi = 0;
    for (int e = 0; e < 3; ++e) {
      float sc = bg[e];
      for (int r = 0; r < 64; ++r) sc += pl[r] * Wg[e * 64 + r];
      if (e == 0 || sc > best) { best = sc; bi = e; }   // first-max semantics
    }
    gidx[b] = bi;
  }
}

// ---------------- Kernel 4: FUSED bicubic-upsample + implicit-GEMM 3x3 conv + bias ----------------
__global__ __launch_bounds__(256) void conv_kernel(const float* __restrict__ z, const u16* __restrict__ cwt,
                                                   const float* __restrict__ cb, const int* __restrict__ gidx,
                                                   u16* __restrict__ cvo) {
  int b = blockIdx.z;
  int e = gidx[b];
  int r = rate_of(e);
  int H = 84 * r;
  int tx = blockIdx.x, ty = blockIdx.y;
  if (tx * 8 >= H || ty * 8 >= H) return;
  __shared__ __align__(16) float patch[8 * 8 * 64];   // 16 KB (P<=8)
  __shared__ u16 halo[100 * 64];                      // 12.8 KB, swizzled
  __shared__ u16 Bw[2][4096];                         // 16 KB, swizzled layout from cwt
  __shared__ float hw[100][8];                        // 3.2 KB
  __shared__ int hidx[100][8];                        // 3.2 KB (patch float-offsets)
  int tid = threadIdx.x, lane = tid & 63, w = tid >> 6;
  const float* zb = z + ((size_t)b * N_ + 1) * 64;
  const u16* wte = cwt + (size_t)e * 9 * 4096;
  gload_lds16(wte + tid * 8, Bw[0] + tid * 8);
  gload_lds16(wte + 2048 + tid * 8, Bw[0] + 2048 + tid * 8);
  if (r == 1) {
    for (int li = tid; li < 800; li += 256) {
      int pix = li >> 3, cq = li & 7;
      int hy = pix / 10, hx = pix - hy * 10;
      int iy = ty * 8 - 1 + hy, ix = tx * 8 - 1 + hx;
      bf16x8 o;
#pragma unroll
      for (int t = 0; t < 8; ++t) o[t] = (__bf16)0.0f;
      if (iy >= 0 && iy < 84 && ix >= 0 && ix < 84) {
        const float* zp = zb + ((size_t)iy * 84 + ix) * 64 + cq * 8;
        float4 q0 = *(const float4*)zp;
        float4 q1 = *(const float4*)(zp + 4);
        o = cvt8(q0, q1);
      }
      *(bf16x8*)(halo + pix * 64 + ((cq ^ (pix & 7)) << 3)) = o;
    }
    __syncthreads();
  } else {
    const int P = (r == 2) ? 8 : 6;
    float inv = 1.0f / (float)r;
    int by = (int)floorf((ty * 8 - 0.5f) * inv - 0.5f) - 1;
    int bx = (int)floorf((tx * 8 - 0.5f) * inv - 0.5f) - 1;
    for (int li = tid; li < P * P * 16; li += 256) {
      int pp_ = li >> 4, f4 = li & 15;
      int py = pp_ / P, px = pp_ - py * P;
      int zr = iclamp(by + py, 0, 83), zc = iclamp(bx + px, 0, 83);
      gload_lds16(zb + ((size_t)zr * 84 + zc) * 64 + f4 * 4, patch + (size_t)li * 4);
    }
    if (tid < 100) {
      int hy = tid / 10, hx = tid - hy * 10;
      int iy = ty * 8 - 1 + hy, ix = tx * 8 - 1 + hx;
      float sy = (iy + 0.5f) * inv - 0.5f;
      float fy = floorf(sy);
      int iy0 = (int)fy;
      float sx = (ix + 0.5f) * inv - 0.5f;
      float fx = floorf(sx);
      int ix0 = (int)fx;
#pragma unroll
      for (int u = 0; u < 4; ++u) {
        hw[tid][u] = cubicw(sy - (fy - 1.0f + u));
        hidx[tid][u] = (iclamp(iy0 - 1 + u, 0, 83) - by) * (P * 64);
        hw[tid][4 + u] = cubicw(sx - (fx - 1.0f + u));
        hidx[tid][4 + u] = (iclamp(ix0 - 1 + u, 0, 83) - bx) * 64;
      }
    }
    __syncthreads();
    for (int li = tid; li < 800; li += 256) {
      int pix = li >> 3, cq = li & 7;
      int hy = pix / 10, hx = pix - hy * 10;
      int iy = ty * 8 - 1 + hy, ix = tx * 8 - 1 + hx;
      bf16x8 o;
#pragma unroll
      for (int t = 0; t < 8; ++t) o[t] = (__bf16)0.0f;
      if (iy >= 0 && iy < H && ix >= 0 && ix < H) {
        float a8[8] = {0.f,0.f,0.f,0.f,0.f,0.f,0.f,0.f};
#pragma unroll
        for (int u = 0; u < 4; ++u) {
          const float* prow = patch + hidx[pix][u] + cq * 8;
          float wyu = hw[pix][u];
#pragma unroll
          for (int v = 0; v < 4; ++v) {
            float wuv = wyu * hw[pix][4 + v];
            const float* pz = prow + hidx[pix][4 + v];
            float4 q0 = *(const float4*)pz;
            float4 q1 = *(const float4*)(pz + 4);
            a8[0] += wuv * q0.x; a8[1] += wuv * q0.y; a8[2] += wuv * q0.z; a8[3] += wuv * q0.w;
            a8[4] += wuv * q1.x; a8[5] += wuv * q1.y; a8[6] += wuv * q1.z; a8[7] += wuv * q1.w;
          }
        }
#pragma unroll
        for (int t = 0; t < 8; ++t) o[t] = (__bf16)a8[t];
      }
      *(bf16x8*)(halo + pix * 64 + ((cq ^ (pix & 7)) << 3)) = o;   // swizzled write
    }
    __syncthreads();
  }
  f32x4 acc[4] = {{0,0,0,0},{0,0,0,0},{0,0,0,0},{0,0,0,0}};
  int p = w * 16 + (lane & 15);
  int py = p >> 3, px = p & 7;
  int kg = lane >> 4;
  for (int tap = 0; tap < 9; ++tap) {
    if (tap < 8) {
      const u16* wt = wte + (size_t)(tap + 1) * 4096;
      gload_lds16(wt + tid * 8, Bw[(tap + 1) & 1] + tid * 8);
      gload_lds16(wt + 2048 + tid * 8, Bw[(tap + 1) & 1] + 2048 + tid * 8);
    }
    int dy = tap / 3, dx = tap - dy * 3;
    int pr = (py + dy) * 10 + (px + dx);
    const u16* bwc = Bw[tap & 1];
#pragma unroll
    for (int kk = 0; kk < 2; ++kk) {
      int ch = kk * 4 + kg;
      bf16x8 a = *(const bf16x8*)(halo + pr * 64 + ((ch ^ (pr & 7)) << 3));
#pragma unroll
      for (int fc = 0; fc < 4; ++fc) {
        int co = fc * 16 + (lane & 15);
        bf16x8 bb = *(const bf16x8*)(bwc + co * 64 + ((ch ^ (co & 7)) << 3));
        acc[fc] = mfma16(a, bb, acc[fc]);
      }
    }
    __syncthreads();
  }
  int crow = (lane >> 4) * 4, ccol = lane & 15;
  u16* cvb = cvo + (size_t)b * UPB_STRIDE;
#pragma unroll
  for (int fc = 0; fc < 4; ++fc) {
    int co = fc * 16 + ccol;
    float bias = cb[e * 64 + co];
#pragma unroll
    for (int i = 0; i < 4; ++i) {
      int pd = w * 16 + crow + i;
      int gy = ty * 8 + (pd >> 3), gx = tx * 8 + (pd & 7);
      if (gy < H && gx < H)
        cvb[((size_t)gy * H + gx) * 64 + co] = f2b(acc[fc][i] + bias);
    }
  }
}

// ---------------- Kernel 5: bicubic downsample * SCALING -> lora rows 1..7056 ----------------
__global__ __launch_bounds__(256) void down_kernel(const u16* __restrict__ cvo, const int* __restrict__ gidx,
                                                   u16* __restrict__ lora) {
  int b = blockIdx.z;
  int r = rate_of(gidx[b]);
  int H = 84 * r;
  int tid = threadIdx.x;
  int c = tid & 63, s = tid >> 6;
  int y = blockIdx.y;
  int x = blockIdx.x * 4 + s;
  float fr = (float)r;
  float sy = (y + 0.5f) * fr - 0.5f;
  float fy = floorf(sy);
  int iy0 = (int)fy;
  float wy[4]; int yi[4];
#pragma unroll
  for (int u = 0; u < 4; ++u) { wy[u] = cubicw(sy - (fy - 1.0f + u)); yi[u] = iclamp(iy0 - 1 + u, 0, H - 1); }
  float sx = (x + 0.5f) * fr - 0.5f;
  float fx = floorf(sx);
  int ix0 = (int)fx;
  float wx[4]; int xi[4];
#pragma unroll
  for (int v = 0; v < 4; ++v) { wx[v] = cubicw(sx - (fx - 1.0f + v)); xi[v] = iclamp(ix0 - 1 + v, 0, H - 1); }
  const u16* cbase = cvo + (size_t)b * UPB_STRIDE;
  float acc = 0.0f;
#pragma unroll
  for (int u = 0; u < 4; ++u)
#pragma unroll
    for (int v = 0; v < 4; ++v)
      acc += wy[u] * wx[v] * b2f(cbase[((size_t)yi[u] * H + xi[v]) * 64 + c]);
  lora[((size_t)b * N_ + 1 + y * 84 + x) * 64 + c] = f2b(acc * SCALING_F);
}

// ---------------- Kernel 6: main GEMM 128x128, BK=64, swizzled (round-9 proven) ----------------
__global__ __launch_bounds__(256) void main_gemm(const u16* __restrict__ xb, const u16* __restrict__ W0b,
                                                 const float* __restrict__ b0, const u16* __restrict__ lora,
                                                 const u16* __restrict__ Wub, float* __restrict__ out) {
  __shared__ u16 As[128 * 64];   // 16 KB
  __shared__ u16 Bs[128 * 64];   // 16 KB
  int tid = threadIdx.x, lane = tid & 63, w = tid >> 6;
  int bid = blockIdx.x;
  int wg = (bid & 7) * 442 + (bid >> 3);      // XCD-chunked swizzle (3536 = 8*442, bijective)
  int row0 = (wg >> 3) * 128, col0 = (wg & 7) * 128;
  int wr = w >> 1, wc = w & 1;
  f32x4 acc[4][4] = {};
  int srow = tid >> 3;          // 0..31
  int schunk = tid & 7;         // 0..7 (16B k-chunks within a 64-elem row)
  int sch8 = ((schunk ^ (srow & 7)) << 3);    // pre-swizzled global k-offset (elems)
  int ar[4]; int br[4];
  u16* aldst[4]; u16* bldst[4];
#pragma unroll
  for (int p = 0; p < 4; ++p) {
    int rr = row0 + p * 32 + srow;
    ar[p] = rr >= MTOT ? MTOT - 1 : rr;
    br[p] = col0 + p * 32 + srow;
    aldst[p] = As + (p * 32 + srow) * 64 + schunk * 8;
    bldst[p] = Bs + (p * 32 + srow) * 64 + schunk * 8;
  }
  for (int k0 = 0; k0 < 1024; k0 += 64) {
#pragma unroll
    for (int p = 0; p < 4; ++p)
      gload_lds16(xb + (size_t)ar[p] * 1024 + k0 + sch8, aldst[p]);
#pragma unroll
    for (int p = 0; p < 4; ++p)
      gload_lds16(W0b + (size_t)br[p] * 1024 + k0 + sch8, bldst[p]);
    __syncthreads();
#pragma unroll
    for (int kk = 0; kk < 2; ++kk) {
      int pc = (((kk << 2) + (lane >> 4)) ^ (lane & 7)) << 3;   // swizzled read chunk
      bf16x8 af[4], bfr[4];
#pragma unroll
      for (int fm = 0; fm < 4; ++fm)
        af[fm] = *(const bf16x8*)(As + (wr * 64 + fm * 16 + (lane & 15)) * 64 + pc);
#pragma unroll
      for (int fc = 0; fc < 4; ++fc)
        bfr[fc] = *(const bf16x8*)(Bs + (wc * 64 + fc * 16 + (lane & 15)) * 64 + pc);
#pragma unroll
      for (int fm = 0; fm < 4; ++fm)
#pragma unroll
        for (int fc = 0; fc < 4; ++fc)
          acc[fm][fc] = mfma16(af[fm], bfr[fc], acc[fm][fc]);
    }
    __syncthreads();
  }
  // lora K-extension: one BK=64 step
#pragma unroll
  for (int p = 0; p < 4; ++p)
    gload_lds16(lora + (size_t)ar[p] * 64 + sch8, aldst[p]);
#pragma unroll
  for (int p = 0; p < 4; ++p)
    gload_lds16(Wub + (size_t)br[p] * 64 + sch8, bldst[p]);
  __syncthreads();
#pragma unroll
  for (int kk = 0; kk < 2; ++kk) {
    int pc = (((kk << 2) + (lane >> 4)) ^ (lane & 7)) << 3;
    bf16x8 af[4], bfr[4];
#pragma unroll
    for (int fm = 0; fm < 4; ++fm)
      af[fm] = *(const bf16x8*)(As + (wr * 64 + fm * 16 + (lane & 15)) * 64 + pc);
#pragma unroll
    for (int fc = 0; fc < 4; ++fc)
      bfr[fc] = *(const bf16x8*)(Bs + (wc * 64 + fc * 16 + (lane & 15)) * 64 + pc);
#pragma unroll
    for (int fm = 0; fm < 4; ++fm)
#pragma unroll
      for (int fc = 0; fc < 4; ++fc)
        acc[fm][fc] = mfma16(af[fm], bfr[fc], acc[fm][fc]);
  }
  __syncthreads();
  int crow = (lane >> 4) * 4, ccol = lane & 15;
#pragma unroll
  for (int fm = 0; fm < 4; ++fm) {
    int grb = row0 + wr * 64 + fm * 16 + crow;
#pragma unroll
    for (int fc = 0; fc < 4; ++fc) {
      int gc = col0 + wc * 64 + fc * 16 + ccol;
      float bias = b0[gc];
#pragma unroll
      for (int i = 0; i < 4; ++i) {
        int gr = grb + i;
        if (gr < MTOT) out[(size_t)gr * 1024 + gc] = acc[fm][fc][i] + bias;
      }
    }
  }
}

extern "C" void kernel_launch(void* const* d_in, const int* in_sizes, int n_in,
                              void* d_out, int out_size, void* d_ws, size_t ws_size,
                              hipStream_t stream) {
  const float* x   = (const float*)d_in[0];
  const float* W0  = (const float*)d_in[1];
  const float* b0  = (const float*)d_in[2];
  const float* Wd  = (const float*)d_in[3];
  const float* Wg  = (const float*)d_in[4];
  const float* bg  = (const float*)d_in[5];
  const float* cw  = (const float*)d_in[6];
  const float* cb  = (const float*)d_in[7];
  const float* Wup = (const float*)d_in[8];
  char* ws = (char*)d_ws;
  float* z    = (float*)(ws + Z_OFF);
  u16* lora   = (u16*)(ws + LORA_OFF);
  int* gidx   = (int*)(ws + GIDX_OFF);
  u16* cwt    = (u16*)(ws + CWT_OFF);
  u16* W0b    = (u16*)(ws + W0B_OFF);
  u16* Wdb    = (u16*)(ws + WDB_OFF);
  u16* Wub    = (u16*)(ws + WUB_OFF);
  float* pp   = (float*)(ws + UP_OFF);   // gate scratch
  u16* cvo    = (u16*)(ws + CO_OFF);
  float* out  = (float*)d_out;

  const bool fast = ws_size >= WS_FAST;          // constant across calls -> deterministic
  u16* xb = fast ? (u16*)(ws + XB_OFF) : (u16*)(ws + CO_OFF);

  cvtall_kernel<<<dim3(1152), dim3(256), 0, stream>>>(W0, Wd, Wup, W0b);
  convwt_kernel<<<dim3(432), dim3(256), 0, stream>>>(cw, cwt);
  zgemm_kernel<<<dim3(883), dim3(256), 0, stream>>>(x, Wdb, z, fast ? xb : nullptr);
  gate1_kernel<<<dim3(56, 8), dim3(256), 0, stream>>>(z, pp);
  gate2_kernel<<<dim3(8), dim3(64), 0, stream>>>(pp, z, Wg, bg, gidx, lora);
  conv_kernel<<<dim3(42, 42, 8), dim3(256), 0, stream>>>(z, cwt, cb, gidx, cvo);
  down_kernel<<<dim3(21, 84, 8), dim3(256), 0, stream>>>(cvo, gidx, lora);
  if (!fast)
    cvtx_kernel<<<dim3(2048), dim3(256), 0, stream>>>(x, xb);  // xb overlays CO (cvo now dead)
  main_gemm<<<dim3(3536), dim3(256), 0, stream>>>(xb, W0b, b0, lora, Wub, out);
}

// Round 13
// 520.297 us; speedup vs baseline: 1.0325x; 1.0325x over previous
//
#include <hip/hip_runtime.h>
#include <stdint.h>

typedef unsigned short u16;
typedef __bf16 bf16x8 __attribute__((ext_vector_type(8)));
typedef float f32x4 __attribute__((ext_vector_type(4)));

#define B_ 8
#define N_ 7057
#define MTOT 56456
#define SCALING_F (1.0f/64.0f)

// ws layout (bytes, 16-aligned).
#define Z_OFF    0ull               // f32 z: 14,452,736
#define LORA_OFF 14452736ull        // bf16 lora: 7,226,368
#define GIDX_OFF 21679104ull        // int gate_idx[8] (+pad)
#define CWT_OFF  21679360ull        // bf16 conv_wt: 221,184 (co-row XOR-swizzled)
#define W0B_OFF  21900544ull        // bf16 W0: 2,097,152
#define WDB_OFF  23997696ull        // bf16 W_down: 131,072
#define WUB_OFF  24128768ull        // bf16 W_up: 131,072
#define UP_OFF   24259840ull        // pp[8][56][64] f32 gate scratch
#define CO_OFF   139865344ull       // bf16 convout: 115,605,504 (ends 255,470,848)
#define XB_OFF   255470848ull       // bf16 xb [MTOT][1024]: 115,621,888 (fast path only)
#define WS_FAST  371092736ull       // bytes needed for fast path
#define UPB_STRIDE ((size_t)112896 * 64)  // per-batch elems (max rate 4)

__device__ __forceinline__ u16 f2b(float f) {
  __bf16 h = (__bf16)f;           // RNE
  union { __bf16 h; u16 u; } v; v.h = h; return v.u;
}
__device__ __forceinline__ float b2f(u16 u) {
  union { uint32_t i; float f; } v; v.i = ((uint32_t)u) << 16; return v.f;
}
__device__ __forceinline__ void gload_lds16(const void* g, void* l) {
  __builtin_amdgcn_global_load_lds(
      (const __attribute__((address_space(1))) uint32_t*)g,
      (__attribute__((address_space(3))) uint32_t*)l, 16, 0, 0);
}
__device__ __forceinline__ f32x4 mfma16(bf16x8 a, bf16x8 b, f32x4 c) {
  return __builtin_amdgcn_mfma_f32_16x16x32_bf16(a, b, c, 0, 0, 0);
}
__device__ __forceinline__ bf16x8 cvt8(float4 a, float4 b) {
  bf16x8 v;
  v[0] = (__bf16)a.x; v[1] = (__bf16)a.y; v[2] = (__bf16)a.z; v[3] = (__bf16)a.w;
  v[4] = (__bf16)b.x; v[5] = (__bf16)b.y; v[6] = (__bf16)b.z; v[7] = (__bf16)b.w;
  return v;
}
__device__ __forceinline__ float cubicw(float t) {
  const float a = -0.75f;
  float at = fabsf(t);
  float w1 = ((a + 2.0f) * at - (a + 3.0f)) * at * at + 1.0f;
  float w2 = (((at - 5.0f) * at + 8.0f) * at - 4.0f) * a;
  return at <= 1.0f ? w1 : (at < 2.0f ? w2 : 0.0f);
}
__device__ __forceinline__ int iclamp(int v, int lo, int hi) { return v < lo ? lo : (v > hi ? hi : v); }
__device__ __forceinline__ int rate_of(int e) { return e == 0 ? 2 : (e == 1 ? 1 : 4); }

// ---------------- Kernel 0: merged f32 -> bf16 weight convert (W0|Wd|Wup contiguous) ----------------
__global__ __launch_bounds__(256) void cvtall_kernel(const float* __restrict__ W0, const float* __restrict__ Wd,
                                                     const float* __restrict__ Wup, u16* __restrict__ dst) {
  int i = (blockIdx.x * 256 + threadIdx.x) * 4;      // total 1,179,648 elems
  if (i >= 1179648) return;
  const float* src;
  if (i < 1048576)      src = W0 + i;
  else if (i < 1114112) src = Wd + (i - 1048576);
  else                  src = Wup + (i - 1114112);
  float4 v = *(const float4*)src;
  union { u16 u[4]; uint2 q; } p;
  p.u[0] = f2b(v.x); p.u[1] = f2b(v.y); p.u[2] = f2b(v.z); p.u[3] = f2b(v.w);
  *(uint2*)(dst + i) = p.q;
}

// ---------------- Kernel 0b (fallback): x f32 -> bf16 grid-stride ----------------
__global__ __launch_bounds__(256) void cvtx_kernel(const float* __restrict__ x, u16* __restrict__ xb) {
  size_t stride = (size_t)gridDim.x * 256 * 8;
  for (size_t i = ((size_t)blockIdx.x * 256 + threadIdx.x) * 8; i < (size_t)MTOT * 1024; i += stride) {
    float4 a = *(const float4*)(x + i);
    float4 b = *(const float4*)(x + i + 4);
    *(bf16x8*)(xb + i) = cvt8(a, b);
  }
}

// ---------------- Kernel 1: z = x @ W_down^T -> f32; side-writes xb (round-9 proven LDS version) ----------------
__global__ __launch_bounds__(256) void zgemm_kernel(const float* __restrict__ x,
                                                    const u16* __restrict__ Wdb,
                                                    float* __restrict__ z,
                                                    u16* __restrict__ xb) {
  __shared__ u16 As[64 * 32];
  __shared__ u16 Bs[64 * 32];
  const int tid = threadIdx.x;
  const int lane = tid & 63;
  const int w = tid >> 6;
  const int row0 = blockIdx.x * 64;
  f32x4 acc[4] = {{0,0,0,0},{0,0,0,0},{0,0,0,0},{0,0,0,0}};
  const int srow = tid >> 2, sk8 = tid & 3;
  int arow = row0 + srow; if (arow >= MTOT) arow = MTOT - 1;
  const float* agf = x + (size_t)arow * 1024 + sk8 * 8;
  const u16* bg = Wdb + (size_t)srow * 1024 + sk8 * 8;
  u16* xbp = xb ? (xb + (size_t)arow * 1024 + sk8 * 8) : nullptr;
  u16* al = As + tid * 8;
  u16* bl = Bs + tid * 8;
  const int klo = (lane >> 4) * 8;
  for (int k0 = 0; k0 < 1024; k0 += 32) {
    gload_lds16(bg + k0, bl);
    float4 q0 = *(const float4*)(agf + k0);
    float4 q1 = *(const float4*)(agf + k0 + 4);
    bf16x8 cv = cvt8(q0, q1);
    *(bf16x8*)al = cv;
    if (xbp) *(bf16x8*)(xbp + k0) = cv;   // bf16 x side-product (fast path)
    __syncthreads();
    bf16x8 a = *(const bf16x8*)(As + (w * 16 + (lane & 15)) * 32 + klo);
#pragma unroll
    for (int fc = 0; fc < 4; ++fc) {
      bf16x8 bb = *(const bf16x8*)(Bs + (fc * 16 + (lane & 15)) * 32 + klo);
      acc[fc] = mfma16(a, bb, acc[fc]);
    }
    __syncthreads();
  }
  const int crow = (lane >> 4) * 4, ccol = lane & 15;
#pragma unroll
  for (int fc = 0; fc < 4; ++fc) {
#pragma unroll
    for (int i = 0; i < 4; ++i) {
      int gr = row0 + w * 16 + crow + i;
      if (gr < MTOT) z[(size_t)gr * 64 + fc * 16 + ccol] = acc[fc][i];
    }
  }
}

// ---------------- Kernel 2a: conv weight transpose -> bf16[e][tap][co][ci-swizzled] ----------------
__global__ __launch_bounds__(256) void convwt_kernel(const float* __restrict__ cw, u16* __restrict__ cwt) {
  int idx = blockIdx.x * 256 + threadIdx.x;          // 3*9*64*64 = 110592 total
  if (idx >= 3 * 9 * 64 * 64) return;
  int ci = idx & 63;
  int co = (idx >> 6) & 63;
  int rest = idx >> 12;           // e*9 + tap
  int tap = rest % 9;
  int e = rest / 9;
  int sw = ((((ci >> 3) ^ (co & 7)) << 3) | (ci & 7));
  cwt[(((size_t)rest * 64) + co) * 64 + sw] = f2b(cw[((size_t)(e * 64 + co) * 64 + ci) * 9 + tap]);
}

// ---------------- Kernel 2b: gate stage 1 — per-chunk partial channel sums ----------------
__global__ __launch_bounds__(256) void gate1_kernel(const float* __restrict__ z, float* __restrict__ pp) {
  int b = blockIdx.y, q = blockIdx.x;   // q in [0,56)
  int tid = threadIdx.x;
  int c = tid & 63, part = tid >> 6;
  const float* zb = z + (size_t)b * N_ * 64;
  int n0 = 1 + q * 126;
  float s = 0.0f;
  for (int n = n0 + part; n < n0 + 126; n += 4) s += zb[(size_t)n * 64 + c];
  __shared__ float red[4][64];
  red[part][c] = s;
  __syncthreads();
  if (tid < 64)
    pp[((size_t)b * 56 + q) * 64 + tid] = red[0][tid] + red[1][tid] + red[2][tid] + red[3][tid];
}

// ---------------- Kernel 2c: gate stage 2 — pooled mean, scores, argmax, cls row ----------------
__global__ __launch_bounds__(64) void gate2_kernel(const float* __restrict__ pp, const float* __restrict__ z,
                                                   const float* __restrict__ Wg, const float* __restrict__ bg,
                                                   int* __restrict__ gidx, u16* __restrict__ lora) {
  int b = blockIdx.x;
  int c = threadIdx.x;                  // 0..63
  float s = 0.0f;
  for (int q = 0; q < 56; ++q) s += pp[((size_t)b * 56 + q) * 64 + c];
  __shared__ float pl[64];
  pl[c] = s * (1.0f / 7056.0f);
  const float* zb = z + (size_t)b * N_ * 64;
  lora[(size_t)b * N_ * 64 + c] = f2b(zb[c]);   // cls_embed, NOT scaled
  __syncthreads();
  if (c == 0) {
    float best = 0.0f; int bi = 0;
    for (int e = 0; e < 3; ++e) {
      float sc = bg[e];
      for (int r = 0; r < 64; ++r) sc += pl[r] * Wg[e * 64 + r];
      if (e == 0 || sc > best) { best = sc; bi = e; }   // first-max semantics
    }
    gidx[b] = bi;
  }
}

// ---------------- Kernel 4: FUSED bicubic-upsample + implicit-GEMM 3x3 conv + bias ----------------
__global__ __launch_bounds__(256) void conv_kernel(const float* __restrict__ z, const u16* __restrict__ cwt,
                                                   const float* __restrict__ cb, const int* __restrict__ gidx,
                                                   u16* __restrict__ cvo) {
  int b = blockIdx.z;
  int e = gidx[b];
  int r = rate_of(e);
  int H = 84 * r;
  int tx = blockIdx.x, ty = blockIdx.y;
  if (tx * 8 >= H || ty * 8 >= H) return;
  __shared__ __align__(16) float patch[8 * 8 * 64];   // 16 KB (P<=8)
  __shared__ u16 halo[100 * 64];                      // 12.8 KB, swizzled
  __shared__ u16 Bw[2][4096];                         // 16 KB, swizzled layout from cwt
  __shared__ float hw[100][8];                        // 3.2 KB
  __shared__ int hidx[100][8];                        // 3.2 KB (patch float-offsets)
  int tid = threadIdx.x, lane = tid & 63, w = tid >> 6;
  const float* zb = z + ((size_t)b * N_ + 1) * 64;
  const u16* wte = cwt + (size_t)e * 9 * 4096;
  gload_lds16(wte + tid * 8, Bw[0] + tid * 8);
  gload_lds16(wte + 2048 + tid * 8, Bw[0] + 2048 + tid * 8);
  if (r == 1) {
    for (int li = tid; li < 800; li += 256) {
      int pix = li >> 3, cq = li & 7;
      int hy = pix / 10, hx = pix - hy * 10;
      int iy = ty * 8 - 1 + hy, ix = tx * 8 - 1 + hx;
      bf16x8 o;
#pragma unroll
      for (int t = 0; t < 8; ++t) o[t] = (__bf16)0.0f;
      if (iy >= 0 && iy < 84 && ix >= 0 && ix < 84) {
        const float* zp = zb + ((size_t)iy * 84 + ix) * 64 + cq * 8;
        float4 q0 = *(const float4*)zp;
        float4 q1 = *(const float4*)(zp + 4);
        o = cvt8(q0, q1);
      }
      *(bf16x8*)(halo + pix * 64 + ((cq ^ (pix & 7)) << 3)) = o;
    }
    __syncthreads();
  } else {
    const int P = (r == 2) ? 8 : 6;
    float inv = 1.0f / (float)r;
    int by = (int)floorf((ty * 8 - 0.5f) * inv - 0.5f) - 1;
    int bx = (int)floorf((tx * 8 - 0.5f) * inv - 0.5f) - 1;
    for (int li = tid; li < P * P * 16; li += 256) {
      int pp_ = li >> 4, f4 = li & 15;
      int py = pp_ / P, px = pp_ - py * P;
      int zr = iclamp(by + py, 0, 83), zc = iclamp(bx + px, 0, 83);
      gload_lds16(zb + ((size_t)zr * 84 + zc) * 64 + f4 * 4, patch + (size_t)li * 4);
    }
    if (tid < 100) {
      int hy = tid / 10, hx = tid - hy * 10;
      int iy = ty * 8 - 1 + hy, ix = tx * 8 - 1 + hx;
      float sy = (iy + 0.5f) * inv - 0.5f;
      float fy = floorf(sy);
      int iy0 = (int)fy;
      float sx = (ix + 0.5f) * inv - 0.5f;
      float fx = floorf(sx);
      int ix0 = (int)fx;
#pragma unroll
      for (int u = 0; u < 4; ++u) {
        hw[tid][u] = cubicw(sy - (fy - 1.0f + u));
        hidx[tid][u] = (iclamp(iy0 - 1 + u, 0, 83) - by) * (P * 64);
        hw[tid][4 + u] = cubicw(sx - (fx - 1.0f + u));
        hidx[tid][4 + u] = (iclamp(ix0 - 1 + u, 0, 83) - bx) * 64;
      }
    }
    __syncthreads();
    for (int li = tid; li < 800; li += 256) {
      int pix = li >> 3, cq = li & 7;
      int hy = pix / 10, hx = pix - hy * 10;
      int iy = ty * 8 - 1 + hy, ix = tx * 8 - 1 + hx;
      bf16x8 o;
#pragma unroll
      for (int t = 0; t < 8; ++t) o[t] = (__bf16)0.0f;
      if (iy >= 0 && iy < H && ix >= 0 && ix < H) {
        float a8[8] = {0.f,0.f,0.f,0.f,0.f,0.f,0.f,0.f};
#pragma unroll
        for (int u = 0; u < 4; ++u) {
          const float* prow = patch + hidx[pix][u] + cq * 8;
          float wyu = hw[pix][u];
#pragma unroll
          for (int v = 0; v < 4; ++v) {
            float wuv = wyu * hw[pix][4 + v];
            const float* pz = prow + hidx[pix][4 + v];
            float4 q0 = *(const float4*)pz;
            float4 q1 = *(const float4*)(pz + 4);
            a8[0] += wuv * q0.x; a8[1] += wuv * q0.y; a8[2] += wuv * q0.z; a8[3] += wuv * q0.w;
            a8[4] += wuv * q1.x; a8[5] += wuv * q1.y; a8[6] += wuv * q1.z; a8[7] += wuv * q1.w;
          }
        }
#pragma unroll
        for (int t = 0; t < 8; ++t) o[t] = (__bf16)a8[t];
      }
      *(bf16x8*)(halo + pix * 64 + ((cq ^ (pix & 7)) << 3)) = o;   // swizzled write
    }
    __syncthreads();
  }
  f32x4 acc[4] = {{0,0,0,0},{0,0,0,0},{0,0,0,0},{0,0,0,0}};
  int p = w * 16 + (lane & 15);
  int py = p >> 3, px = p & 7;
  int kg = lane >> 4;
  for (int tap = 0; tap < 9; ++tap) {
    if (tap < 8) {
      const u16* wt = wte + (size_t)(tap + 1) * 4096;
      gload_lds16(wt + tid * 8, Bw[(tap + 1) & 1] + tid * 8);
      gload_lds16(wt + 2048 + tid * 8, Bw[(tap + 1) & 1] + 2048 + tid * 8);
    }
    int dy = tap / 3, dx = tap - dy * 3;
    int pr = (py + dy) * 10 + (px + dx);
    const u16* bwc = Bw[tap & 1];
#pragma unroll
    for (int kk = 0; kk < 2; ++kk) {
      int ch = kk * 4 + kg;
      bf16x8 a = *(const bf16x8*)(halo + pr * 64 + ((ch ^ (pr & 7)) << 3));
#pragma unroll
      for (int fc = 0; fc < 4; ++fc) {
        int co = fc * 16 + (lane & 15);
        bf16x8 bb = *(const bf16x8*)(bwc + co * 64 + ((ch ^ (co & 7)) << 3));
        acc[fc] = mfma16(a, bb, acc[fc]);
      }
    }
    __syncthreads();
  }
  int crow = (lane >> 4) * 4, ccol = lane & 15;
  u16* cvb = cvo + (size_t)b * UPB_STRIDE;
#pragma unroll
  for (int fc = 0; fc < 4; ++fc) {
    int co = fc * 16 + ccol;
    float bias = cb[e * 64 + co];
#pragma unroll
    for (int i = 0; i < 4; ++i) {
      int pd = w * 16 + crow + i;
      int gy = ty * 8 + (pd >> 3), gx = tx * 8 + (pd & 7);
      if (gy < H && gx < H)
        cvb[((size_t)gy * H + gx) * 64 + co] = f2b(acc[fc][i] + bias);
    }
  }
}

// ---------------- Kernel 5: bicubic downsample * SCALING -> lora rows 1..7056 ----------------
__global__ __launch_bounds__(256) void down_kernel(const u16* __restrict__ cvo, const int* __restrict__ gidx,
                                                   u16* __restrict__ lora) {
  int b = blockIdx.z;
  int r = rate_of(gidx[b]);
  int H = 84 * r;
  int tid = threadIdx.x;
  int c = tid & 63, s = tid >> 6;
  int y = blockIdx.y;
  int x = blockIdx.x * 4 + s;
  float fr = (float)r;
  float sy = (y + 0.5f) * fr - 0.5f;
  float fy = floorf(sy);
  int iy0 = (int)fy;
  float wy[4]; int yi[4];
#pragma unroll
  for (int u = 0; u < 4; ++u) { wy[u] = cubicw(sy - (fy - 1.0f + u)); yi[u] = iclamp(iy0 - 1 + u, 0, H - 1); }
  float sx = (x + 0.5f) * fr - 0.5f;
  float fx = floorf(sx);
  int ix0 = (int)fx;
  float wx[4]; int xi[4];
#pragma unroll
  for (int v = 0; v < 4; ++v) { wx[v] = cubicw(sx - (fx - 1.0f + v)); xi[v] = iclamp(ix0 - 1 + v, 0, H - 1); }
  const u16* cbase = cvo + (size_t)b * UPB_STRIDE;
  float acc = 0.0f;
#pragma unroll
  for (int u = 0; u < 4; ++u)
#pragma unroll
    for (int v = 0; v < 4; ++v)
      acc += wy[u] * wx[v] * b2f(cbase[((size_t)yi[u] * H + xi[v]) * 64 + c]);
  lora[((size_t)b * N_ + 1 + y * 84 + x) * 64 + c] = f2b(acc * SCALING_F);
}

// ---------------- Kernel 6: main GEMM 128x128, BK=64, swizzled (round-9 proven) ----------------
__global__ __launch_bounds__(256) void main_gemm(const u16* __restrict__ xb, const u16* __restrict__ W0b,
                                                 const float* __restrict__ b0, const u16* __restrict__ lora,
                                                 const u16* __restrict__ Wub, float* __restrict__ out) {
  __shared__ u16 As[128 * 64];   // 16 KB
  __shared__ u16 Bs[128 * 64];   // 16 KB
  int tid = threadIdx.x, lane = tid & 63, w = tid >> 6;
  int bid = blockIdx.x;
  int wg = (bid & 7) * 442 + (bid >> 3);      // XCD-chunked swizzle (3536 = 8*442, bijective)
  int row0 = (wg >> 3) * 128, col0 = (wg & 7) * 128;
  int wr = w >> 1, wc = w & 1;
  f32x4 acc[4][4] = {};
  int srow = tid >> 3;          // 0..31
  int schunk = tid & 7;         // 0..7 (16B k-chunks within a 64-elem row)
  int sch8 = ((schunk ^ (srow & 7)) << 3);    // pre-swizzled global k-offset (elems)
  int ar[4]; int br[4];
  u16* aldst[4]; u16* bldst[4];
#pragma unroll
  for (int p = 0; p < 4; ++p) {
    int rr = row0 + p * 32 + srow;
    ar[p] = rr >= MTOT ? MTOT - 1 : rr;
    br[p] = col0 + p * 32 + srow;
    aldst[p] = As + (p * 32 + srow) * 64 + schunk * 8;
    bldst[p] = Bs + (p * 32 + srow) * 64 + schunk * 8;
  }
  for (int k0 = 0; k0 < 1024; k0 += 64) {
#pragma unroll
    for (int p = 0; p < 4; ++p)
      gload_lds16(xb + (size_t)ar[p] * 1024 + k0 + sch8, aldst[p]);
#pragma unroll
    for (int p = 0; p < 4; ++p)
      gload_lds16(W0b + (size_t)br[p] * 1024 + k0 + sch8, bldst[p]);
    __syncthreads();
#pragma unroll
    for (int kk = 0; kk < 2; ++kk) {
      int pc = (((kk << 2) + (lane >> 4)) ^ (lane & 7)) << 3;   // swizzled read chunk
      bf16x8 af[4], bfr[4];
#pragma unroll
      for (int fm = 0; fm < 4; ++fm)
        af[fm] = *(const bf16x8*)(As + (wr * 64 + fm * 16 + (lane & 15)) * 64 + pc);
#pragma unroll
      for (int fc = 0; fc < 4; ++fc)
        bfr[fc] = *(const bf16x8*)(Bs + (wc * 64 + fc * 16 + (lane & 15)) * 64 + pc);
#pragma unroll
      for (int fm = 0; fm < 4; ++fm)
#pragma unroll
        for (int fc = 0; fc < 4; ++fc)
          acc[fm][fc] = mfma16(af[fm], bfr[fc], acc[fm][fc]);
    }
    __syncthreads();
  }
  // lora K-extension: one BK=64 step
#pragma unroll
  for (int p = 0; p < 4; ++p)
    gload_lds16(lora + (size_t)ar[p] * 64 + sch8, aldst[p]);
#pragma unroll
  for (int p = 0; p < 4; ++p)
    gload_lds16(Wub + (size_t)br[p] * 64 + sch8, bldst[p]);
  __syncthreads();
#pragma unroll
  for (int kk = 0; kk < 2; ++kk) {
    int pc = (((kk << 2) + (lane >> 4)) ^ (lane & 7)) << 3;
    bf16x8 af[4], bfr[4];
#pragma unroll
    for (int fm = 0; fm < 4; ++fm)
      af[fm] = *(const bf16x8*)(As + (wr * 64 + fm * 16 + (lane & 15)) * 64 + pc);
#pragma unroll
    for (int fc = 0; fc < 4; ++fc)
      bfr[fc] = *(const bf16x8*)(Bs + (wc * 64 + fc * 16 + (lane & 15)) * 64 + pc);
#pragma unroll
    for (int fm = 0; fm < 4; ++fm)
#pragma unroll
      for (int fc = 0; fc < 4; ++fc)
        acc[fm][fc] = mfma16(af[fm], bfr[fc], acc[fm][fc]);
  }
  __syncthreads();
  int crow = (lane >> 4) * 4, ccol = lane & 15;
#pragma unroll
  for (int fm = 0; fm < 4; ++fm) {
    int grb = row0 + wr * 64 + fm * 16 + crow;
#pragma unroll
    for (int fc = 0; fc < 4; ++fc) {
      int gc = col0 + wc * 64 + fc * 16 + ccol;
      float bias = b0[gc];
#pragma unroll
      for (int i = 0; i < 4; ++i) {
        int gr = grb + i;
        if (gr < MTOT) out[(size_t)gr * 1024 + gc] = acc[fm][fc][i] + bias;
      }
    }
  }
}

extern "C" void kernel_launch(void* const* d_in, const int* in_sizes, int n_in,
                              void* d_out, int out_size, void* d_ws, size_t ws_size,
                              hipStream_t stream) {
  const float* x   = (const float*)d_in[0];
  const float* W0  = (const float*)d_in[1];
  const float* b0  = (const float*)d_in[2];
  const float* Wd  = (const float*)d_in[3];
  const float* Wg  = (const float*)d_in[4];
  const float* bg  = (const float*)d_in[5];
  const float* cw  = (const float*)d_in[6];
  const float* cb  = (const float*)d_in[7];
  const float* Wup = (const float*)d_in[8];
  char* ws = (char*)d_ws;
  float* z    = (float*)(ws + Z_OFF);
  u16* lora   = (u16*)(ws + LORA_OFF);
  int* gidx   = (int*)(ws + GIDX_OFF);
  u16* cwt    = (u16*)(ws + CWT_OFF);
  u16* W0b    = (u16*)(ws + W0B_OFF);
  u16* Wdb    = (u16*)(ws + WDB_OFF);
  u16* Wub    = (u16*)(ws + WUB_OFF);
  float* pp   = (float*)(ws + UP_OFF);   // gate scratch
  u16* cvo    = (u16*)(ws + CO_OFF);
  float* out  = (float*)d_out;

  const bool fast = ws_size >= WS_FAST;          // constant across calls -> deterministic
  u16* xb = fast ? (u16*)(ws + XB_OFF) : (u16*)(ws + CO_OFF);

  cvtall_kernel<<<dim3(1152), dim3(256), 0, stream>>>(W0, Wd, Wup, W0b);
  convwt_kernel<<<dim3(432), dim3(256), 0, stream>>>(cw, cwt);
  zgemm_kernel<<<dim3(883), dim3(256), 0, stream>>>(x, Wdb, z, fast ? xb : nullptr);
  gate1_kernel<<<dim3(56, 8), dim3(256), 0, stream>>>(z, pp);
  gate2_kernel<<<dim3(8), dim3(64), 0, stream>>>(pp, z, Wg, bg, gidx, lora);
  conv_kernel<<<dim3(42, 42, 8), dim3(256), 0, stream>>>(z, cwt, cb, gidx, cvo);
  down_kernel<<<dim3(21, 84, 8), dim3(256), 0, stream>>>(cvo, gidx, lora);
  if (!fast)
    cvtx_kernel<<<dim3(2048), dim3(256), 0, stream>>>(x, xb);  // xb overlays CO (cvo now dead)
  main_gemm<<<dim3(3536), dim3(256), 0, stream>>>(xb, W0b, b0, lora, Wub, out);
}

// Round 15
// 508.880 us; speedup vs baseline: 1.0557x; 1.0224x over previous
//
#include <hip/hip_runtime.h>
#include <stdint.h>

typedef unsigned short u16;
typedef __bf16 bf16x8 __attribute__((ext_vector_type(8)));
typedef float f32x4 __attribute__((ext_vector_type(4)));

#define B_ 8
#define N_ 7057
#define MTOT 56456
#define SCALING_F (1.0f/64.0f)

// ws layout (bytes, 16-aligned).
#define Z_OFF    0ull               // f32 z: 14,452,736
#define LORA_OFF 14452736ull        // bf16 lora: 7,226,368
#define GIDX_OFF 21679104ull        // int gate_idx[8] (+pad)
#define CWT_OFF  21679360ull        // bf16 conv_wt: 221,184 (co-row XOR-swizzled)
#define W0B_OFF  21900544ull        // bf16 W0: 2,097,152
#define WDB_OFF  23997696ull        // bf16 W_down: 131,072
#define WUB_OFF  24128768ull        // bf16 W_up: 131,072
#define UP_OFF   24259840ull        // pp[8][56][64] f32 gate scratch
#define CO_OFF   139865344ull       // bf16 convout: 115,605,504 (ends 255,470,848)
#define XB_OFF   255470848ull       // bf16 xb [MTOT][1024]: 115,621,888 (fast path only)
#define WS_FAST  371092736ull       // bytes needed for fast path
#define UPB_STRIDE ((size_t)112896 * 64)  // per-batch elems (max rate 4)

__device__ __forceinline__ u16 f2b(float f) {
  __bf16 h = (__bf16)f;           // RNE
  union { __bf16 h; u16 u; } v; v.h = h; return v.u;
}
__device__ __forceinline__ float b2f(u16 u) {
  union { uint32_t i; float f; } v; v.i = ((uint32_t)u) << 16; return v.f;
}
__device__ __forceinline__ void gload_lds16(const void* g, void* l) {
  __builtin_amdgcn_global_load_lds(
      (const __attribute__((address_space(1))) uint32_t*)g,
      (__attribute__((address_space(3))) uint32_t*)l, 16, 0, 0);
}
__device__ __forceinline__ f32x4 mfma16(bf16x8 a, bf16x8 b, f32x4 c) {
  return __builtin_amdgcn_mfma_f32_16x16x32_bf16(a, b, c, 0, 0, 0);
}
__device__ __forceinline__ bf16x8 cvt8(float4 a, float4 b) {
  bf16x8 v;
  v[0] = (__bf16)a.x; v[1] = (__bf16)a.y; v[2] = (__bf16)a.z; v[3] = (__bf16)a.w;
  v[4] = (__bf16)b.x; v[5] = (__bf16)b.y; v[6] = (__bf16)b.z; v[7] = (__bf16)b.w;
  return v;
}
__device__ __forceinline__ float cubicw(float t) {
  const float a = -0.75f;
  float at = fabsf(t);
  float w1 = ((a + 2.0f) * at - (a + 3.0f)) * at * at + 1.0f;
  float w2 = (((at - 5.0f) * at + 8.0f) * at - 4.0f) * a;
  return at <= 1.0f ? w1 : (at < 2.0f ? w2 : 0.0f);
}
__device__ __forceinline__ int iclamp(int v, int lo, int hi) { return v < lo ? lo : (v > hi ? hi : v); }
__device__ __forceinline__ int rate_of(int e) { return e == 0 ? 2 : (e == 1 ? 1 : 4); }

// ---------------- Kernel 0: merged f32 -> bf16 weight convert (W0|Wd|Wup contiguous) ----------------
__global__ __launch_bounds__(256) void cvtall_kernel(const float* __restrict__ W0, const float* __restrict__ Wd,
                                                     const float* __restrict__ Wup, u16* __restrict__ dst) {
  int i = (blockIdx.x * 256 + threadIdx.x) * 4;      // total 1,179,648 elems
  if (i >= 1179648) return;
  const float* src;
  if (i < 1048576)      src = W0 + i;
  else if (i < 1114112) src = Wd + (i - 1048576);
  else                  src = Wup + (i - 1114112);
  float4 v = *(const float4*)src;
  union { u16 u[4]; uint2 q; } p;
  p.u[0] = f2b(v.x); p.u[1] = f2b(v.y); p.u[2] = f2b(v.z); p.u[3] = f2b(v.w);
  *(uint2*)(dst + i) = p.q;
}

// ---------------- Kernel 0b (fallback): x f32 -> bf16 grid-stride ----------------
__global__ __launch_bounds__(256) void cvtx_kernel(const float* __restrict__ x, u16* __restrict__ xb) {
  size_t stride = (size_t)gridDim.x * 256 * 8;
  for (size_t i = ((size_t)blockIdx.x * 256 + threadIdx.x) * 8; i < (size_t)MTOT * 1024; i += stride) {
    float4 a = *(const float4*)(x + i);
    float4 b = *(const float4*)(x + i + 4);
    *(bf16x8*)(xb + i) = cvt8(a, b);
  }
}

// ---------------- Kernel 1: z = x @ W_down^T -> f32; side-writes xb (round-9 proven LDS version) ----------------
__global__ __launch_bounds__(256) void zgemm_kernel(const float* __restrict__ x,
                                                    const u16* __restrict__ Wdb,
                                                    float* __restrict__ z,
                                                    u16* __restrict__ xb) {
  __shared__ u16 As[64 * 32];
  __shared__ u16 Bs[64 * 32];
  const int tid = threadIdx.x;
  const int lane = tid & 63;
  const int w = tid >> 6;
  const int row0 = blockIdx.x * 64;
  f32x4 acc[4] = {{0,0,0,0},{0,0,0,0},{0,0,0,0},{0,0,0,0}};
  const int srow = tid >> 2, sk8 = tid & 3;
  int arow = row0 + srow; if (arow >= MTOT) arow = MTOT - 1;
  const float* agf = x + (size_t)arow * 1024 + sk8 * 8;
  const u16* bg = Wdb + (size_t)srow * 1024 + sk8 * 8;
  u16* xbp = xb ? (xb + (size_t)arow * 1024 + sk8 * 8) : nullptr;
  u16* al = As + tid * 8;
  u16* bl = Bs + tid * 8;
  const int klo = (lane >> 4) * 8;
  for (int k0 = 0; k0 < 1024; k0 += 32) {
    gload_lds16(bg + k0, bl);
    float4 q0 = *(const float4*)(agf + k0);
    float4 q1 = *(const float4*)(agf + k0 + 4);
    bf16x8 cv = cvt8(q0, q1);
    *(bf16x8*)al = cv;
    if (xbp) *(bf16x8*)(xbp + k0) = cv;   // bf16 x side-product (fast path)
    __syncthreads();
    bf16x8 a = *(const bf16x8*)(As + (w * 16 + (lane & 15)) * 32 + klo);
#pragma unroll
    for (int fc = 0; fc < 4; ++fc) {
      bf16x8 bb = *(const bf16x8*)(Bs + (fc * 16 + (lane & 15)) * 32 + klo);
      acc[fc] = mfma16(a, bb, acc[fc]);
    }
    __syncthreads();
  }
  const int crow = (lane >> 4) * 4, ccol = lane & 15;
#pragma unroll
  for (int fc = 0; fc < 4; ++fc) {
#pragma unroll
    for (int i = 0; i < 4; ++i) {
      int gr = row0 + w * 16 + crow + i;
      if (gr < MTOT) z[(size_t)gr * 64 + fc * 16 + ccol] = acc[fc][i];
    }
  }
}

// ---------------- Kernel 2a: conv weight transpose -> bf16[e][tap][co][ci-swizzled] ----------------
__global__ __launch_bounds__(256) void convwt_kernel(const float* __restrict__ cw, u16* __restrict__ cwt) {
  int idx = blockIdx.x * 256 + threadIdx.x;          // 3*9*64*64 = 110592 total
  if (idx >= 3 * 9 * 64 * 64) return;
  int ci = idx & 63;
  int co = (idx >> 6) & 63;
  int rest = idx >> 12;           // e*9 + tap
  int tap = rest % 9;
  int e = rest / 9;
  int sw = ((((ci >> 3) ^ (co & 7)) << 3) | (ci & 7));
  cwt[(((size_t)rest * 64) + co) * 64 + sw] = f2b(cw[((size_t)(e * 64 + co) * 64 + ci) * 9 + tap]);
}

// ---------------- Kernel 2b: gate stage 1 — per-chunk partial channel sums ----------------
__global__ __launch_bounds__(256) void gate1_kernel(const float* __restrict__ z, float* __restrict__ pp) {
  int b = blockIdx.y, q = blockIdx.x;   // q in [0,56)
  int tid = threadIdx.x;
  int c = tid & 63, part = tid >> 6;
  const float* zb = z + (size_t)b * N_ * 64;
  int n0 = 1 + q * 126;
  float s = 0.0f;
  for (int n = n0 + part; n < n0 + 126; n += 4) s += zb[(size_t)n * 64 + c];
  __shared__ float red[4][64];
  red[part][c] = s;
  __syncthreads();
  if (tid < 64)
    pp[((size_t)b * 56 + q) * 64 + tid] = red[0][tid] + red[1][tid] + red[2][tid] + red[3][tid];
}

// ---------------- Kernel 2c: gate stage 2 — pooled mean, scores, argmax, cls row ----------------
__global__ __launch_bounds__(64) void gate2_kernel(const float* __restrict__ pp, const float* __restrict__ z,
                                                   const float* __restrict__ Wg, const float* __restrict__ bg,
                                                   int* __restrict__ gidx, u16* __restrict__ lora) {
  int b = blockIdx.x;
  int c = threadIdx.x;                  // 0..63
  float s = 0.0f;
  for (int q = 0; q < 56; ++q) s += pp[((size_t)b * 56 + q) * 64 + c];
  __shared__ float pl[64];
  pl[c] = s * (1.0f / 7056.0f);
  const float* zb = z + (size_t)b * N_ * 64;
  lora[(size_t)b * N_ * 64 + c] = f2b(zb[c]);   // cls_embed, NOT scaled
  __syncthreads();
  if (c == 0) {
    float best = 0.0f; int bi = 0;
    for (int e = 0; e < 3; ++e) {
      float sc = bg[e];
      for (int r = 0; r < 64; ++r) sc += pl[r] * Wg[e * 64 + r];
      if (e == 0 || sc > best) { best = sc; bi = e; }   // first-max semantics
    }
    gidx[b] = bi;
  }
}

// ---------------- Kernel 4: FUSED bicubic-upsample + implicit-GEMM 3x3 conv + bias ----------------
__global__ __launch_bounds__(256) void conv_kernel(const float* __restrict__ z, const u16* __restrict__ cwt,
                                                   const float* __restrict__ cb, const int* __restrict__ gidx,
                                                   u16* __restrict__ cvo) {
  int b = blockIdx.z;
  int e = gidx[b];
  int r = rate_of(e);
  int H = 84 * r;
  int tx = blockIdx.x, ty = blockIdx.y;
  if (tx * 8 >= H || ty * 8 >= H) return;
  __shared__ __align__(16) float patch[8 * 8 * 64];   // 16 KB (P<=8)
  __shared__ u16 halo[100 * 64];                      // 12.8 KB, swizzled
  __shared__ u16 Bw[2][4096];                         // 16 KB, swizzled layout from cwt
  __shared__ float hw[100][8];                        // 3.2 KB
  __shared__ int hidx[100][8];                        // 3.2 KB (patch float-offsets)
  int tid = threadIdx.x, lane = tid & 63, w = tid >> 6;
  const float* zb = z + ((size_t)b * N_ + 1) * 64;
  const u16* wte = cwt + (size_t)e * 9 * 4096;
  gload_lds16(wte + tid * 8, Bw[0] + tid * 8);
  gload_lds16(wte + 2048 + tid * 8, Bw[0] + 2048 + tid * 8);
  if (r == 1) {
    for (int li = tid; li < 800; li += 256) {
      int pix = li >> 3, cq = li & 7;
      int hy = pix / 10, hx = pix - hy * 10;
      int iy = ty * 8 - 1 + hy, ix = tx * 8 - 1 + hx;
      bf16x8 o;
#pragma unroll
      for (int t = 0; t < 8; ++t) o[t] = (__bf16)0.0f;
      if (iy >= 0 && iy < 84 && ix >= 0 && ix < 84) {
        const float* zp = zb + ((size_t)iy * 84 + ix) * 64 + cq * 8;
        float4 q0 = *(const float4*)zp;
        float4 q1 = *(const float4*)(zp + 4);
        o = cvt8(q0, q1);
      }
      *(bf16x8*)(halo + pix * 64 + ((cq ^ (pix & 7)) << 3)) = o;
    }
    __syncthreads();
  } else {
    const int P = (r == 2) ? 8 : 6;
    float inv = 1.0f / (float)r;
    int by = (int)floorf((ty * 8 - 0.5f) * inv - 0.5f) - 1;
    int bx = (int)floorf((tx * 8 - 0.5f) * inv - 0.5f) - 1;
    for (int li = tid; li < P * P * 16; li += 256) {
      int pp_ = li >> 4, f4 = li & 15;
      int py = pp_ / P, px = pp_ - py * P;
      int zr = iclamp(by + py, 0, 83), zc = iclamp(bx + px, 0, 83);
      gload_lds16(zb + ((size_t)zr * 84 + zc) * 64 + f4 * 4, patch + (size_t)li * 4);
    }
    if (tid < 100) {
      int hy = tid / 10, hx = tid - hy * 10;
      int iy = ty * 8 - 1 + hy, ix = tx * 8 - 1 + hx;
      float sy = (iy + 0.5f) * inv - 0.5f;
      float fy = floorf(sy);
      int iy0 = (int)fy;
      float sx = (ix + 0.5f) * inv - 0.5f;
      float fx = floorf(sx);
      int ix0 = (int)fx;
#pragma unroll
      for (int u = 0; u < 4; ++u) {
        hw[tid][u] = cubicw(sy - (fy - 1.0f + u));
        hidx[tid][u] = (iclamp(iy0 - 1 + u, 0, 83) - by) * (P * 64);
        hw[tid][4 + u] = cubicw(sx - (fx - 1.0f + u));
        hidx[tid][4 + u] = (iclamp(ix0 - 1 + u, 0, 83) - bx) * 64;
      }
    }
    __syncthreads();
    for (int li = tid; li < 800; li += 256) {
      int pix = li >> 3, cq = li & 7;
      int hy = pix / 10, hx = pix - hy * 10;
      int iy = ty * 8 - 1 + hy, ix = tx * 8 - 1 + hx;
      bf16x8 o;
#pragma unroll
      for (int t = 0; t < 8; ++t) o[t] = (__bf16)0.0f;
      if (iy >= 0 && iy < H && ix >= 0 && ix < H) {
        float a8[8] = {0.f,0.f,0.f,0.f,0.f,0.f,0.f,0.f};
#pragma unroll
        for (int u = 0; u < 4; ++u) {
          const float* prow = patch + hidx[pix][u] + cq * 8;
          float wyu = hw[pix][u];
#pragma unroll
          for (int v = 0; v < 4; ++v) {
            float wuv = wyu * hw[pix][4 + v];
            const float* pz = prow + hidx[pix][4 + v];
            float4 q0 = *(const float4*)pz;
            float4 q1 = *(const float4*)(pz + 4);
            a8[0] += wuv * q0.x; a8[1] += wuv * q0.y; a8[2] += wuv * q0.z; a8[3] += wuv * q0.w;
            a8[4] += wuv * q1.x; a8[5] += wuv * q1.y; a8[6] += wuv * q1.z; a8[7] += wuv * q1.w;
          }
        }
#pragma unroll
        for (int t = 0; t < 8; ++t) o[t] = (__bf16)a8[t];
      }
      *(bf16x8*)(halo + pix * 64 + ((cq ^ (pix & 7)) << 3)) = o;   // swizzled write
    }
    __syncthreads();
  }
  f32x4 acc[4] = {{0,0,0,0},{0,0,0,0},{0,0,0,0},{0,0,0,0}};
  int p = w * 16 + (lane & 15);
  int py = p >> 3, px = p & 7;
  int kg = lane >> 4;
  for (int tap = 0; tap < 9; ++tap) {
    if (tap < 8) {
      const u16* wt = wte + (size_t)(tap + 1) * 4096;
      gload_lds16(wt + tid * 8, Bw[(tap + 1) & 1] + tid * 8);
      gload_lds16(wt + 2048 + tid * 8, Bw[(tap + 1) & 1] + 2048 + tid * 8);
    }
    int dy = tap / 3, dx = tap - dy * 3;
    int pr = (py + dy) * 10 + (px + dx);
    const u16* bwc = Bw[tap & 1];
#pragma unroll
    for (int kk = 0; kk < 2; ++kk) {
      int ch = kk * 4 + kg;
      bf16x8 a = *(const bf16x8*)(halo + pr * 64 + ((ch ^ (pr & 7)) << 3));
#pragma unroll
      for (int fc = 0; fc < 4; ++fc) {
        int co = fc * 16 + (lane & 15);
        bf16x8 bb = *(const bf16x8*)(bwc + co * 64 + ((ch ^ (co & 7)) << 3));
        acc[fc] = mfma16(a, bb, acc[fc]);
      }
    }
    __syncthreads();
  }
  int crow = (lane >> 4) * 4, ccol = lane & 15;
  u16* cvb = cvo + (size_t)b * UPB_STRIDE;
#pragma unroll
  for (int fc = 0; fc < 4; ++fc) {
    int co = fc * 16 + ccol;
    float bias = cb[e * 64 + co];
#pragma unroll
    for (int i = 0; i < 4; ++i) {
      int pd = w * 16 + crow + i;
      int gy = ty * 8 + (pd >> 3), gx = tx * 8 + (pd & 7);
      if (gy < H && gx < H)
        cvb[((size_t)gy * H + gx) * 64 + co] = f2b(acc[fc][i] + bias);
    }
  }
}

// ---------------- Kernel 5: bicubic downsample * SCALING -> lora rows 1..7056 ----------------
__global__ __launch_bounds__(256) void down_kernel(const u16* __restrict__ cvo, const int* __restrict__ gidx,
                                                   u16* __restrict__ lora) {
  int b = blockIdx.z;
  int r = rate_of(gidx[b]);
  int H = 84 * r;
  int tid = threadIdx.x;
  int c = tid & 63, s = tid >> 6;
  int y = blockIdx.y;
  int x = blockIdx.x * 4 + s;
  float fr = (float)r;
  float sy = (y + 0.5f) * fr - 0.5f;
  float fy = floorf(sy);
  int iy0 = (int)fy;
  float wy[4]; int yi[4];
#pragma unroll
  for (int u = 0; u < 4; ++u) { wy[u] = cubicw(sy - (fy - 1.0f + u)); yi[u] = iclamp(iy0 - 1 + u, 0, H - 1); }
  float sx = (x + 0.5f) * fr - 0.5f;
  float fx = floorf(sx);
  int ix0 = (int)fx;
  float wx[4]; int xi[4];
#pragma unroll
  for (int v = 0; v < 4; ++v) { wx[v] = cubicw(sx - (fx - 1.0f + v)); xi[v] = iclamp(ix0 - 1 + v, 0, H - 1); }
  const u16* cbase = cvo + (size_t)b * UPB_STRIDE;
  float acc = 0.0f;
#pragma unroll
  for (int u = 0; u < 4; ++u)
#pragma unroll
    for (int v = 0; v < 4; ++v)
      acc += wy[u] * wx[v] * b2f(cbase[((size_t)yi[u] * H + xi[v]) * 64 + c]);
  lora[((size_t)b * N_ + 1 + y * 84 + x) * 64 + c] = f2b(acc * SCALING_F);
}

// ---------------- Kernel 6: main GEMM 128x128, BK=64, swizzled (round-9/13 proven) ----------------
__global__ __launch_bounds__(256) void main_gemm(const u16* __restrict__ xb, const u16* __restrict__ W0b,
                                                 const float* __restrict__ b0, const u16* __restrict__ lora,
                                                 const u16* __restrict__ Wub, float* __restrict__ out) {
  __shared__ u16 As[128 * 64];   // 16 KB
  __shared__ u16 Bs[128 * 64];   // 16 KB
  int tid = threadIdx.x, lane = tid & 63, w = tid >> 6;
  int bid = blockIdx.x;
  int wg = (bid & 7) * 442 + (bid >> 3);      // XCD-chunked swizzle (3536 = 8*442, bijective)
  int row0 = (wg >> 3) * 128, col0 = (wg & 7) * 128;
  int wr = w >> 1, wc = w & 1;
  f32x4 acc[4][4] = {};
  int srow = tid >> 3;          // 0..31
  int schunk = tid & 7;         // 0..7 (16B k-chunks within a 64-elem row)
  int sch8 = ((schunk ^ (srow & 7)) << 3);    // pre-swizzled global k-offset (elems)
  int ar[4]; int br[4];
  u16* aldst[4]; u16* bldst[4];
#pragma unroll
  for (int p = 0; p < 4; ++p) {
    int rr = row0 + p * 32 + srow;
    ar[p] = rr >= MTOT ? MTOT - 1 : rr;
    br[p] = col0 + p * 32 + srow;
    aldst[p] = As + (p * 32 + srow) * 64 + schunk * 8;
    bldst[p] = Bs + (p * 32 + srow) * 64 + schunk * 8;
  }
  for (int k0 = 0; k0 < 1024; k0 += 64) {
#pragma unroll
    for (int p = 0; p < 4; ++p)
      gload_lds16(xb + (size_t)ar[p] * 1024 + k0 + sch8, aldst[p]);
#pragma unroll
    for (int p = 0; p < 4; ++p)
      gload_lds16(W0b + (size_t)br[p] * 1024 + k0 + sch8, bldst[p]);
    __syncthreads();
#pragma unroll
    for (int kk = 0; kk < 2; ++kk) {
      int pc = (((kk << 2) + (lane >> 4)) ^ (lane & 7)) << 3;   // swizzled read chunk
      bf16x8 af[4], bfr[4];
#pragma unroll
      for (int fm = 0; fm < 4; ++fm)
        af[fm] = *(const bf16x8*)(As + (wr * 64 + fm * 16 + (lane & 15)) * 64 + pc);
#pragma unroll
      for (int fc = 0; fc < 4; ++fc)
        bfr[fc] = *(const bf16x8*)(Bs + (wc * 64 + fc * 16 + (lane & 15)) * 64 + pc);
#pragma unroll
      for (int fm = 0; fm < 4; ++fm)
#pragma unroll
        for (int fc = 0; fc < 4; ++fc)
          acc[fm][fc] = mfma16(af[fm], bfr[fc], acc[fm][fc]);
    }
    __syncthreads();
  }
  // lora K-extension: one BK=64 step
#pragma unroll
  for (int p = 0; p < 4; ++p)
    gload_lds16(lora + (size_t)ar[p] * 64 + sch8, aldst[p]);
#pragma unroll
  for (int p = 0; p < 4; ++p)
    gload_lds16(Wub + (size_t)br[p] * 64 + sch8, bldst[p]);
  __syncthreads();
#pragma unroll
  for (int kk = 0; kk < 2; ++kk) {
    int pc = (((kk << 2) + (lane >> 4)) ^ (lane & 7)) << 3;
    bf16x8 af[4], bfr[4];
#pragma unroll
    for (int fm = 0; fm < 4; ++fm)
      af[fm] = *(const bf16x8*)(As + (wr * 64 + fm * 16 + (lane & 15)) * 64 + pc);
#pragma unroll
    for (int fc = 0; fc < 4; ++fc)
      bfr[fc] = *(const bf16x8*)(Bs + (wc * 64 + fc * 16 + (lane & 15)) * 64 + pc);
#pragma unroll
    for (int fm = 0; fm < 4; ++fm)
#pragma unroll
      for (int fc = 0; fc < 4; ++fc)
        acc[fm][fc] = mfma16(af[fm], bfr[fc], acc[fm][fc]);
  }
  __syncthreads();
  int crow = (lane >> 4) * 4, ccol = lane & 15;
#pragma unroll
  for (int fm = 0; fm < 4; ++fm) {
    int grb = row0 + wr * 64 + fm * 16 + crow;
#pragma unroll
    for (int fc = 0; fc < 4; ++fc) {
      int gc = col0 + wc * 64 + fc * 16 + ccol;
      float bias = b0[gc];
#pragma unroll
      for (int i = 0; i < 4; ++i) {
        int gr = grb + i;
        if (gr < MTOT) out[(size_t)gr * 1024 + gc] = acc[fm][fc][i] + bias;
      }
    }
  }
}

extern "C" void kernel_launch(void* const* d_in, const int* in_sizes, int n_in,
                              void* d_out, int out_size, void* d_ws, size_t ws_size,
                              hipStream_t stream) {
  const float* x   = (const float*)d_in[0];
  const float* W0  = (const float*)d_in[1];
  const float* b0  = (const float*)d_in[2];
  const float* Wd  = (const float*)d_in[3];
  const float* Wg  = (const float*)d_in[4];
  const float* bg  = (const float*)d_in[5];
  const float* cw  = (const float*)d_in[6];
  const float* cb  = (const float*)d_in[7];
  const float* Wup = (const float*)d_in[8];
  char* ws = (char*)d_ws;
  float* z    = (float*)(ws + Z_OFF);
  u16* lora   = (u16*)(ws + LORA_OFF);
  int* gidx   = (int*)(ws + GIDX_OFF);
  u16* cwt    = (u16*)(ws + CWT_OFF);
  u16* W0b    = (u16*)(ws + W0B_OFF);
  u16* Wdb    = (u16*)(ws + WDB_OFF);
  u16* Wub    = (u16*)(ws + WUB_OFF);
  float* pp   = (float*)(ws + UP_OFF);   // gate scratch
  u16* cvo    = (u16*)(ws + CO_OFF);
  float* out  = (float*)d_out;

  const bool fast = ws_size >= WS_FAST;          // constant across calls -> deterministic
  u16* xb = fast ? (u16*)(ws + XB_OFF) : (u16*)(ws + CO_OFF);

  cvtall_kernel<<<dim3(1152), dim3(256), 0, stream>>>(W0, Wd, Wup, W0b);
  convwt_kernel<<<dim3(432), dim3(256), 0, stream>>>(cw, cwt);
  zgemm_kernel<<<dim3(883), dim3(256), 0, stream>>>(x, Wdb, z, fast ? xb : nullptr);
  gate1_kernel<<<dim3(56, 8), dim3(256), 0, stream>>>(z, pp);
  gate2_kernel<<<dim3(8), dim3(64), 0, stream>>>(pp, z, Wg, bg, gidx, lora);
  conv_kernel<<<dim3(42, 42, 8), dim3(256), 0, stream>>>(z, cwt, cb, gidx, cvo);
  down_kernel<<<dim3(21, 84, 8), dim3(256), 0, stream>>>(cvo, gidx, lora);
  if (!fast)
    cvtx_kernel<<<dim3(2048), dim3(256), 0, stream>>>(x, xb);  // xb overlays CO (cvo now dead)
  main_gemm<<<dim3(3536), dim3(256), 0, stream>>>(xb, W0b, b0, lora, Wub, out);
}